// Round 5
// baseline (790.208 us; speedup 1.0000x reference)
//
#include <hip/hip_runtime.h>
#include <hip/hip_bf16.h>

// B=2048 rows, T=2048 steps, H=32. Wave = ONE batch row; lane = (k, half).
// Thread holds k-slice [16*hf, 16*hf+16) of gate rows {k,32+k,64+k,96+k} =
// 64 weight floats. 2048 waves = 2 waves/SIMD; amdgpu_waves_per_eu(2,2) tells
// the RA that more occupancy is impossible, so it may use up to 256 VGPRs and
// keep the weights resident (R3 failure: RA minimized to 64 VGPRs + spills).
// Cross-half reduce = __builtin_amdgcn_permlane32_swap in the order-insensitive
// form sum(r[0],r[1]); packed math via __builtin_elementwise_fma only (the R4
// raw-asm forms are banned: op_sel_hi / hazard handling belong to codegen).

#define Bsz 2048
#define Tsz 2048
#define Hsz 32

typedef float v2f __attribute__((ext_vector_type(2)));

__device__ __forceinline__ float fast_rcp(float x) { return __builtin_amdgcn_rcpf(x); }
__device__ __forceinline__ float fast_exp2(float x) { return __builtin_amdgcn_exp2f(x); }
__device__ __forceinline__ float fast_sigmoid(float x) {
    return fast_rcp(1.0f + fast_exp2(-1.442695041f * x));
}
__device__ __forceinline__ float fast_tanh(float x) {
    return __fmaf_rn(2.0f, fast_rcp(1.0f + fast_exp2(-2.885390082f * x)), -1.0f);
}

__device__ __forceinline__ v2f pkfma(v2f a, v2f b, v2f c) {
#if __has_builtin(__builtin_elementwise_fma)
    return __builtin_elementwise_fma(a, b, c);
#else
    v2f r; r.x = __fmaf_rn(a.x, b.x, c.x); r.y = __fmaf_rn(a.y, b.y, c.y); return r;
#endif
}

// s[l] + s[l^32] in every lane; order-insensitive (sum of both swap outputs).
__device__ __forceinline__ float half_sum(float s) {
#if __has_builtin(__builtin_amdgcn_permlane32_swap)
    auto r = __builtin_amdgcn_permlane32_swap(__float_as_uint(s), __float_as_uint(s),
                                              false, false);
    return __uint_as_float(r[0]) + __uint_as_float(r[1]);
#else
    return s + __shfl_xor(s, 32);
#endif
}

__global__ __launch_bounds__(256)
__attribute__((amdgpu_waves_per_eu(2, 2)))
void lstm_fwd_kernel(
    const float* __restrict__ x,      // (B, T)
    const float* __restrict__ w_ih,   // (4H, 1)
    const float* __restrict__ w_hh,   // (4H, H)
    const float* __restrict__ b_ih,   // (4H,)
    const float* __restrict__ b_hh,   // (4H,)
    float* __restrict__ out)          // (B, T*H)
{
    __shared__ float hbuf[4][32];     // one 128B h-line per wave(row)

    const int lane = threadIdx.x & 63;
    const int k    = lane & 31;
    const int hf   = lane >> 5;                                   // half: 0/1
    const int wv   = __builtin_amdgcn_readfirstlane((int)(threadIdx.x >> 6));
    const int b    = blockIdx.x * 4 + wv;

    // ---- weights: 4 gates x 8 v2f = this thread's 16-float k-slice ----
    v2f   W[4][8];
    float wi[4], bs[4];
#pragma unroll
    for (int g = 0; g < 4; ++g) {
        const int j = g * 32 + k;
        wi[g] = w_ih[j];
        bs[g] = b_ih[j] + b_hh[j];
        const float4* wr =
            reinterpret_cast<const float4*>(w_hh + (size_t)j * 32 + hf * 16);
#pragma unroll
        for (int q = 0; q < 4; ++q) {
            float4 v = wr[q];
            W[g][2 * q]     = (v2f){v.x, v.y};
            W[g][2 * q + 1] = (v2f){v.z, v.w};
        }
    }

    float c = 0.0f, h = 0.0f, hprev = 0.0f;
    hbuf[wv][k] = 0.0f;

    const float* xrow  = x + (size_t)b * Tsz;
    float*       obase = out + (size_t)b * (size_t)(Tsz * Hsz);
    const int    sidx  = hf * 32 + k;   // paired-store offset (2 t-rows/store)

    float xs[8], xn[8];
#pragma unroll
    for (int j = 0; j < 8; ++j) xs[j] = xrow[j];

    for (int t0 = 0; t0 < Tsz; t0 += 8) {
        const int tn = (t0 + 8 < Tsz) ? (t0 + 8) : t0;
#pragma unroll
        for (int j = 0; j < 8; ++j) xn[j] = xrow[tn + j];

#pragma unroll
        for (int tt = 0; tt < 8; ++tt) {
            // previous h, this thread's 16-float slice (4x broadcast b128)
            const float4* hr =
                reinterpret_cast<const float4*>(&hbuf[wv][hf * 16]);
            float4 h0 = hr[0], h1 = hr[1], h2 = hr[2], h3 = hr[3];
            v2f hv[8];
            hv[0] = (v2f){h0.x, h0.y}; hv[1] = (v2f){h0.z, h0.w};
            hv[2] = (v2f){h1.x, h1.y}; hv[3] = (v2f){h1.z, h1.w};
            hv[4] = (v2f){h2.x, h2.y}; hv[5] = (v2f){h2.z, h2.w};
            hv[6] = (v2f){h3.x, h3.y}; hv[7] = (v2f){h3.z, h3.w};
            const float xt = xs[tt];

            float p[4];
#pragma unroll
            for (int g = 0; g < 4; ++g) {
                v2f a = pkfma(W[g][0], hv[0], (v2f){0.0f, 0.0f});
                a = pkfma(W[g][1], hv[1], a);
                a = pkfma(W[g][2], hv[2], a);
                a = pkfma(W[g][3], hv[3], a);
                a = pkfma(W[g][4], hv[4], a);
                a = pkfma(W[g][5], hv[5], a);
                a = pkfma(W[g][6], hv[6], a);
                a = pkfma(W[g][7], hv[7], a);
                p[g] = half_sum(a.x + a.y) + __fmaf_rn(wi[g], xt, bs[g]);
            }

            const float i_ = fast_sigmoid(p[0]);
            const float f_ = fast_sigmoid(p[1]);
            const float g_ = fast_tanh(p[2]);
            const float o_ = fast_sigmoid(p[3]);

            c = __fmaf_rn(f_, c, i_ * g_);
            h = o_ * fast_tanh(c);

            hbuf[wv][k] = h;              // both halves, same value: benign

            if (tt & 1) {                 // paired store: t-1 (hf0), t (hf1)
                const float v = hf ? h : hprev;
                obase[(size_t)(t0 + tt - 1) * Hsz + sidx] = v;
            } else {
                hprev = h;
            }
        }
#pragma unroll
        for (int j = 0; j < 8; ++j) xs[j] = xn[j];
    }
}

extern "C" void kernel_launch(void* const* d_in, const int* in_sizes, int n_in,
                              void* d_out, int out_size, void* d_ws, size_t ws_size,
                              hipStream_t stream) {
    const float* x    = (const float*)d_in[0];
    const float* w_ih = (const float*)d_in[1];
    const float* w_hh = (const float*)d_in[2];
    const float* b_ih = (const float*)d_in[3];
    const float* b_hh = (const float*)d_in[4];
    float* out = (float*)d_out;

    dim3 grid(Bsz / 4);   // 512 blocks = 2 per CU -> 2 waves/SIMD
    dim3 block(256);      // 4 waves, each = one batch row (32 k x 2 halves)
    lstm_fwd_kernel<<<grid, block, 0, stream>>>(x, w_ih, w_hh, b_ih, b_hh, out);
}

// Round 6
// 610.182 us; speedup vs baseline: 1.2950x; 1.2950x over previous
//
#include <hip/hip_runtime.h>
#include <hip/hip_bf16.h>
#include <hip/hip_fp16.h>

// B=2048 rows, T=2048 steps, H=32. Wave = ONE batch row; lane = (k, half).
// Dots in f16 via v_dot2_f32_f16 (full-rate, 2 MAC/instr, fp32 accumulate):
// halves the fp32 FMA issue floor AND halves weight registers (32 VGPRs ->
// residency pressure gone). h shared across halves through LDS as f16.
// All cross-half traffic via __builtin_amdgcn_permlane32_swap (R5-verified):
//   plswap(a,a) -> (low-half-origin value, high-half-origin value) in ALL
//   lanes, so gate reduce = 2 swaps + 2 adds and the split-activation
//   exchange (i,g)/(f,o) costs 2 swaps, zero selects.

#define Bsz 2048
#define Tsz 2048
#define Hsz 32

typedef _Float16 v2h __attribute__((ext_vector_type(2)));

__device__ __forceinline__ float fast_rcp(float x) { return __builtin_amdgcn_rcpf(x); }
__device__ __forceinline__ float fast_exp2(float x) { return __builtin_amdgcn_exp2f(x); }
__device__ __forceinline__ float fast_tanh(float x) {
    return __fmaf_rn(2.0f, fast_rcp(1.0f + fast_exp2(-2.885390082f * x)), -1.0f);
}

__device__ __forceinline__ float fdot2(v2h a, v2h b, float c) {
#if __has_builtin(__builtin_amdgcn_fdot2)
    return __builtin_amdgcn_fdot2(a, b, c, false);
#else
    return __fmaf_rn((float)a.x, (float)b.x, __fmaf_rn((float)a.y, (float)b.y, c));
#endif
}

// r0 = low-half-origin values (everywhere), r1 = high-half-origin values.
__device__ __forceinline__ void plswap(float a, float b, float& r0, float& r1) {
#if __has_builtin(__builtin_amdgcn_permlane32_swap)
    auto r = __builtin_amdgcn_permlane32_swap(__float_as_uint(a), __float_as_uint(b),
                                              false, false);
    r0 = __uint_as_float(r[0]);
    r1 = __uint_as_float(r[1]);
#else
    const bool hi = (threadIdx.x & 32) != 0;
    r0 = hi ? __shfl_xor(b, 32) : a;
    r1 = hi ? b : __shfl_xor(a, 32);
#endif
}

__global__ __launch_bounds__(256, 2) void lstm_fwd_kernel(
    const float* __restrict__ x,      // (B, T)
    const float* __restrict__ w_ih,   // (4H, 1)
    const float* __restrict__ w_hh,   // (4H, H)
    const float* __restrict__ b_ih,   // (4H,)
    const float* __restrict__ b_hh,   // (4H,)
    float* __restrict__ out)          // (B, T*H)
{
    __shared__ _Float16 hbuf[4][32];  // one 64B f16 h-line per wave(row)

    const int lane = threadIdx.x & 63;
    const int k    = lane & 31;
    const int hf   = lane >> 5;                       // half: 0/1
    const int wv   = threadIdx.x >> 6;                // wave = row in block
    const int b    = blockIdx.x * 4 + wv;

    // ---- f16 weights: 4 gates x 8 v2h = 16-float k-slice each (32 VGPRs) ----
    v2h W[4][8];
#pragma unroll
    for (int g = 0; g < 4; ++g) {
        const float4* wr =
            reinterpret_cast<const float4*>(w_hh + (size_t)(g * 32 + k) * 32 + hf * 16);
#pragma unroll
        for (int q = 0; q < 4; ++q) {
            float4 v = wr[q];
            W[g][2 * q]     = (v2h){(_Float16)v.x, (_Float16)v.y};
            W[g][2 * q + 1] = (v2h){(_Float16)v.z, (_Float16)v.w};
        }
    }
    // per-thread bias/x weights for the TWO gates this half activates
    const int gA = hf ? 2 : 0, gB = gA + 1;
    const float wiA = w_ih[gA * 32 + k], bsA = b_ih[gA * 32 + k] + b_hh[gA * 32 + k];
    const float wiB = w_ih[gB * 32 + k], bsB = b_ih[gB * 32 + k] + b_hh[gB * 32 + k];

    // unified activation: a = A1*rcp(1+exp2(B1*v)) + C1
    // hf0 -> sigmoid (i-gate), hf1 -> tanh (g-gate); second value always sigmoid
    const float B1 = hf ? -2.885390082f : -1.442695041f;
    const float A1 = hf ? 2.0f : 1.0f;
    const float C1 = hf ? -1.0f : 0.0f;

    float c = 0.0f, h = 0.0f, hprev = 0.0f;
    hbuf[wv][k] = (_Float16)0.0f;     // both halves, same value: benign

    const float4* xq = reinterpret_cast<const float4*>(x + (size_t)b * Tsz);
    float* op = out + (size_t)b * (size_t)(Tsz * Hsz) + hf * 32 + k; // paired-store ptr

    union Uq { uint4 q; v2h h2[4]; };

    auto steps8 = [&](float4 xA, float4 xB) {
        const float xts[8] = {xA.x, xA.y, xA.z, xA.w, xB.x, xB.y, xB.z, xB.w};
#pragma unroll
        for (int tt = 0; tt < 8; ++tt) {
            // previous h: this half's 16 f16 values as 2x ds_read_b128 (broadcast)
            Uq u0 = *reinterpret_cast<const Uq*>(&hbuf[wv][hf * 16]);
            Uq u1 = *reinterpret_cast<const Uq*>(&hbuf[wv][hf * 16 + 8]);
            const float xt = xts[tt];

            float s0 = 0.0f, s1 = 0.0f, s2 = 0.0f, s3 = 0.0f;
#pragma unroll
            for (int j = 0; j < 4; ++j) {
                s0 = fdot2(W[0][j], u0.h2[j], s0);
                s1 = fdot2(W[1][j], u0.h2[j], s1);
                s2 = fdot2(W[2][j], u0.h2[j], s2);
                s3 = fdot2(W[3][j], u0.h2[j], s3);
            }
#pragma unroll
            for (int j = 0; j < 4; ++j) {
                s0 = fdot2(W[0][4 + j], u1.h2[j], s0);
                s1 = fdot2(W[1][4 + j], u1.h2[j], s1);
                s2 = fdot2(W[2][4 + j], u1.h2[j], s2);
                s3 = fdot2(W[3][4 + j], u1.h2[j], s3);
            }

            // cross-half reduce: hf0 gets full p0/p1, hf1 gets full p2/p3
            float r0, r1;
            plswap(s0, s2, r0, r1);
            const float v1 = r0 + r1 + __fmaf_rn(wiA, xt, bsA);
            plswap(s1, s3, r0, r1);
            const float v2 = r0 + r1 + __fmaf_rn(wiB, xt, bsB);

            // own-half activations (6 trans/step total instead of 10)
            const float a1 = __fmaf_rn(A1, fast_rcp(1.0f + fast_exp2(B1 * v1)), C1);
            const float a2 = fast_rcp(1.0f + fast_exp2(-1.442695041f * v2));

            // exchange: i,f from low-half origin; g,o from high-half origin
            float i_, g_, f_, o_;
            plswap(a1, a1, i_, g_);   // i_ = sig(p0), g_ = tanh(p2), all lanes
            plswap(a2, a2, f_, o_);   // f_ = sig(p1), o_ = sig(p3), all lanes

            c = __fmaf_rn(f_, c, i_ * g_);
            h = o_ * fast_tanh(c);

            hbuf[wv][k] = (_Float16)h;            // next step's input

            if (tt & 1) {                         // paired store: rows t-1, t
                *op = hf ? h : hprev;
                op += 64;
            } else {
                hprev = h;
            }
        }
    };

    // software-pipelined x tiles: 16 steps per iter, prefetch one tile ahead
    float4 xc0 = xq[0], xc1 = xq[1];
    const int last_base = (Tsz >> 2) - 2;
#pragma unroll 1
    for (int t0 = 0; t0 < Tsz; t0 += 16) {
        const int i1 = (t0 >> 2) + 2;             // steps t0+8 .. t0+15
        float4 xn0 = xq[i1], xn1 = xq[i1 + 1];
        steps8(xc0, xc1);
        const int i2 = ((t0 >> 2) + 4 > last_base) ? last_base : (t0 >> 2) + 4;
        float4 xm0 = xq[i2], xm1 = xq[i2 + 1];    // clamped (dead on last iter)
        steps8(xn0, xn1);
        xc0 = xm0; xc1 = xm1;
    }
}

extern "C" void kernel_launch(void* const* d_in, const int* in_sizes, int n_in,
                              void* d_out, int out_size, void* d_ws, size_t ws_size,
                              hipStream_t stream) {
    const float* x    = (const float*)d_in[0];
    const float* w_ih = (const float*)d_in[1];
    const float* w_hh = (const float*)d_in[2];
    const float* b_ih = (const float*)d_in[3];
    const float* b_hh = (const float*)d_in[4];
    float* out = (float*)d_out;

    dim3 grid(Bsz / 4);   // 512 blocks = 2 per CU -> 2 waves/SIMD
    dim3 block(256);      // 4 waves, each = one batch row (32 k x 2 halves)
    lstm_fwd_kernel<<<grid, block, 0, stream>>>(x, w_ih, w_hh, b_ih, b_hh, out);
}